// Round 1
// baseline (606.424 us; speedup 1.0000x reference)
//
#include <hip/hip_runtime.h>

typedef __attribute__((ext_vector_type(8))) __bf16 bf16x8;
typedef __attribute__((ext_vector_type(4))) __bf16 bf16x4;
typedef __attribute__((ext_vector_type(4))) float floatx4;

#define MFMA16x16x32 __builtin_amdgcn_mfma_f32_16x16x32_bf16

// ---------------- cast fp32 -> bf16 (vectorized x4) ----------------
__global__ void cast_bf16_kernel(const float* __restrict__ src, __bf16* __restrict__ dst, int n4) {
  int i = blockIdx.x * blockDim.x + threadIdx.x;
  if (i < n4) {
    const float4* s4 = (const float4*)src;
    float4 v = s4[i];
    bf16x4 o;
    o[0] = (__bf16)v.x; o[1] = (__bf16)v.y; o[2] = (__bf16)v.z; o[3] = (__bf16)v.w;
    *(bf16x4*)(dst + (size_t)i * 4) = o;
  }
}

// ---------------- GEMM: C(M,N) fp32 = A(M,K) @ B(N,K)^T, bf16 inputs ----------------
// 128x128 tile, BK=64, 4 waves each 64x64 (4x4 of 16x16 MFMA).
__global__ __launch_bounds__(256) void gemm_bt_128(const __bf16* __restrict__ A,
                                                   const __bf16* __restrict__ Bw,
                                                   float* __restrict__ C,
                                                   int M, int N, int K) {
  __shared__ __bf16 As[128][72];  // 144 B row stride (16B aligned)
  __shared__ __bf16 Bs[128][72];
  const int tid = threadIdx.x;
  const int wave = tid >> 6, lane = tid & 63;
  const int quad = lane >> 4, l16 = lane & 15;
  const int wm = (wave >> 1) * 64, wn = (wave & 1) * 64;
  const int row0 = blockIdx.y * 128, col0 = blockIdx.x * 128;
  floatx4 acc[4][4] = {};
  for (int k0 = 0; k0 < K; k0 += 64) {
#pragma unroll
    for (int i = 0; i < 4; i++) {
      int ch = tid + 256 * i;       // 0..1023
      int r = ch >> 3, seg = ch & 7; // 8 segs of 8 bf16 = 64
      *(bf16x8*)&As[r][seg * 8] = *(const bf16x8*)(A + (size_t)(row0 + r) * K + k0 + seg * 8);
      *(bf16x8*)&Bs[r][seg * 8] = *(const bf16x8*)(Bw + (size_t)(col0 + r) * K + k0 + seg * 8);
    }
    __syncthreads();
#pragma unroll
    for (int kk = 0; kk < 64; kk += 32) {
      bf16x8 af[4], bfr[4];
#pragma unroll
      for (int mt = 0; mt < 4; mt++) af[mt] = *(const bf16x8*)&As[wm + mt * 16 + l16][kk + quad * 8];
#pragma unroll
      for (int nt = 0; nt < 4; nt++) bfr[nt] = *(const bf16x8*)&Bs[wn + nt * 16 + l16][kk + quad * 8];
#pragma unroll
      for (int mt = 0; mt < 4; mt++)
#pragma unroll
        for (int nt = 0; nt < 4; nt++)
          acc[mt][nt] = MFMA16x16x32(af[mt], bfr[nt], acc[mt][nt], 0, 0, 0);
    }
    __syncthreads();
  }
#pragma unroll
  for (int mt = 0; mt < 4; mt++)
#pragma unroll
    for (int nt = 0; nt < 4; nt++)
#pragma unroll
      for (int r = 0; r < 4; r++) {
        int row = row0 + wm + mt * 16 + quad * 4 + r;
        int col = col0 + wn + nt * 16 + l16;
        C[(size_t)row * N + col] = acc[mt][nt][r];
      }
}

// ---------------- RoPE + split qkv fp32 -> q/k/v bf16 ----------------
// qkv: (4096, 3072) fp32 row-major. q: cols 0..2048, k: 2048..2560, v: 2560..3072.
__global__ void rope_kernel(const float* __restrict__ qkv, const float* __restrict__ cs,
                            const float* __restrict__ sn, __bf16* __restrict__ qb,
                            __bf16* __restrict__ kb, __bf16* __restrict__ vb) {
  int idx = blockIdx.x * blockDim.x + threadIdx.x;  // 4096*1536
  int row = idx / 1536, slot = idx - row * 1536;
  int t = row & 2047;
  const float* base = qkv + (size_t)row * 3072;
  if (slot < 1024) {               // q pairs
    int i = slot & 63;
    float x0 = base[2 * slot], x1 = base[2 * slot + 1];
    float c = cs[t * 64 + i], s = sn[t * 64 + i];
    qb[(size_t)row * 2048 + 2 * slot]     = (__bf16)(x0 * c - x1 * s);
    qb[(size_t)row * 2048 + 2 * slot + 1] = (__bf16)(x0 * s + x1 * c);
  } else if (slot < 1280) {        // k pairs
    int ks = slot - 1024;
    int i = ks & 63;
    float x0 = base[2048 + 2 * ks], x1 = base[2048 + 2 * ks + 1];
    float c = cs[t * 64 + i], s = sn[t * 64 + i];
    kb[(size_t)row * 512 + 2 * ks]     = (__bf16)(x0 * c - x1 * s);
    kb[(size_t)row * 512 + 2 * ks + 1] = (__bf16)(x0 * s + x1 * c);
  } else {                         // v cast
    int vs = slot - 1280;
    vb[(size_t)row * 512 + 2 * vs]     = (__bf16)base[2560 + 2 * vs];
    vb[(size_t)row * 512 + 2 * vs + 1] = (__bf16)base[2560 + 2 * vs + 1];
  }
}

// ---------------- Flash attention, causal, GQA ----------------
// grid: (qblk=32, h=16, b=2), 256 thr = 4 waves, wave w owns q rows [qblk*64+w*16, +16)
__global__ __launch_bounds__(256) void attn_kernel(const __bf16* __restrict__ qb,
                                                   const __bf16* __restrict__ kb,
                                                   const __bf16* __restrict__ vb,
                                                   __bf16* __restrict__ yb) {
  const int qblk = blockIdx.x, h = blockIdx.y, b = blockIdx.z;
  const int kvh = h >> 2;
  const int tid = threadIdx.x, wave = tid >> 6, lane = tid & 63;
  const int quad = lane >> 4, l16 = lane & 15;
  const int q0 = qblk * 64 + wave * 16;
  __shared__ __bf16 Ks[32][136];   // [key][dim], 272 B stride
  __shared__ __bf16 Vt[128][40];   // [dim][key] transposed, 80 B stride
  __shared__ __bf16 Ps[4][16][40]; // per-wave P tile [qrow][key]
  bf16x8 qf[4];
  {
    const __bf16* qrow = qb + (size_t)(b * 2048 + q0 + l16) * 2048 + h * 128;
#pragma unroll
    for (int kc = 0; kc < 4; kc++) qf[kc] = *(const bf16x8*)(qrow + kc * 32 + quad * 8);
  }
  floatx4 o[8] = {};
  float m_r[4], l_r[4];
#pragma unroll
  for (int r = 0; r < 4; r++) { m_r[r] = -1e30f; l_r[r] = 0.f; }
  const float scale = 0.08838834764831845f;  // 1/sqrt(128)
  const int kend = qblk * 64 + 64;
  for (int s0 = 0; s0 < kend; s0 += 32) {
    __syncthreads();
    {
      // stage K block: 32 keys x 128 dims
#pragma unroll
      for (int i = 0; i < 2; i++) {
        int ch = tid + 256 * i;
        int key = ch >> 4, seg = ch & 15;
        *(bf16x8*)&Ks[key][seg * 8] =
            *(const bf16x8*)(kb + (size_t)(b * 2048 + s0 + key) * 512 + kvh * 128 + seg * 8);
      }
      // stage V transposed
      int key = tid >> 3, ds = tid & 7;
      const __bf16* vrow = vb + (size_t)(b * 2048 + s0 + key) * 512 + kvh * 128 + ds * 16;
      bf16x8 v0 = *(const bf16x8*)vrow;
      bf16x8 v1 = *(const bf16x8*)(vrow + 8);
#pragma unroll
      for (int j = 0; j < 8; j++) Vt[ds * 16 + j][key] = v0[j];
#pragma unroll
      for (int j = 0; j < 8; j++) Vt[ds * 16 + 8 + j][key] = v1[j];
    }
    __syncthreads();
    if (s0 <= q0 + 15) {  // wave-uniform: any valid key in this block
      floatx4 sacc[2] = {};
#pragma unroll
      for (int kc = 0; kc < 4; kc++) {
        bf16x8 b0 = *(const bf16x8*)&Ks[l16][kc * 32 + quad * 8];
        bf16x8 b1 = *(const bf16x8*)&Ks[16 + l16][kc * 32 + quad * 8];
        sacc[0] = MFMA16x16x32(qf[kc], b0, sacc[0], 0, 0, 0);
        sacc[1] = MFMA16x16x32(qf[kc], b1, sacc[1], 0, 0, 0);
      }
      float sf[2][4];
#pragma unroll
      for (int nt = 0; nt < 2; nt++)
#pragma unroll
        for (int r = 0; r < 4; r++) {
          float sv = sacc[nt][r] * scale;
          int keyg = s0 + nt * 16 + l16;
          int qg = q0 + quad * 4 + r;
          sf[nt][r] = (keyg > qg) ? -1e30f : sv;
        }
      float alpha[4];
#pragma unroll
      for (int r = 0; r < 4; r++) {
        float mb = fmaxf(sf[0][r], sf[1][r]);
#pragma unroll
        for (int off = 8; off >= 1; off >>= 1) mb = fmaxf(mb, __shfl_xor(mb, off));
        float mn = fmaxf(m_r[r], mb);
        float a = __expf(m_r[r] - mn);
        float p0 = __expf(sf[0][r] - mn);
        float p1 = __expf(sf[1][r] - mn);
        sf[0][r] = p0; sf[1][r] = p1;
        float ls = p0 + p1;
#pragma unroll
        for (int off = 8; off >= 1; off >>= 1) ls += __shfl_xor(ls, off);
        l_r[r] = l_r[r] * a + ls;
        m_r[r] = mn;
        alpha[r] = a;
      }
#pragma unroll
      for (int dt = 0; dt < 8; dt++)
#pragma unroll
        for (int r = 0; r < 4; r++) o[dt][r] *= alpha[r];
      // P (D-layout) -> LDS -> A-layout
#pragma unroll
      for (int nt = 0; nt < 2; nt++)
#pragma unroll
        for (int r = 0; r < 4; r++)
          Ps[wave][quad * 4 + r][nt * 16 + l16] = (__bf16)sf[nt][r];
      bf16x8 pa = *(const bf16x8*)&Ps[wave][l16][quad * 8];
#pragma unroll
      for (int dt = 0; dt < 8; dt++) {
        bf16x8 vf = *(const bf16x8*)&Vt[dt * 16 + l16][quad * 8];
        o[dt] = MFMA16x16x32(pa, vf, o[dt], 0, 0, 0);
      }
    }
  }
  float inv[4];
#pragma unroll
  for (int r = 0; r < 4; r++) inv[r] = 1.f / l_r[r];
#pragma unroll
  for (int dt = 0; dt < 8; dt++)
#pragma unroll
    for (int r = 0; r < 4; r++) {
      int qg = q0 + quad * 4 + r;
      yb[(size_t)(b * 2048 + qg) * 2048 + h * 128 + dt * 16 + l16] = (__bf16)(o[dt][r] * inv[r]);
    }
}

// ---------------- host ----------------
extern "C" void kernel_launch(void* const* d_in, const int* in_sizes, int n_in,
                              void* d_out, int out_size, void* d_ws, size_t ws_size,
                              hipStream_t stream) {
  const float* x  = (const float*)d_in[0];
  const float* fc = (const float*)d_in[1];
  const float* fs = (const float*)d_in[2];
  const float* wq = (const float*)d_in[3];
  const float* wk = (const float*)d_in[4];
  const float* wv = (const float*)d_in[5];
  const float* wo = (const float*)d_in[6];
  float* out = (float*)d_out;
  char* ws = (char*)d_ws;

  __bf16* xb   = (__bf16*)(ws);              // 4096x2048 bf16 (16.78 MB)
  __bf16* wqkv = (__bf16*)(ws + 16777216);   // 3072x2048 bf16 (12.58 MB)
  __bf16* wob  = (__bf16*)(ws + 29360128);   // 2048x2048 bf16 (8.39 MB)
  float*  qkv  = (float*) (ws + 37748736);   // 4096x3072 fp32 (50.33 MB)
  __bf16* kbuf = (__bf16*)(ws + 88080384);   // 4096x512 bf16
  __bf16* vbuf = (__bf16*)(ws + 92274688);   // 4096x512 bf16
  __bf16* qbuf = xb;                          // alias: xb dead after GEMM1
  __bf16* ybuf = (__bf16*)(ws + 37748736);    // alias: qkv dead after rope

  // casts
  cast_bf16_kernel<<<8388608 / 1024, 256, 0, stream>>>(x, xb, 8388608 / 4);
  cast_bf16_kernel<<<4194304 / 1024, 256, 0, stream>>>(wq, wqkv, 4194304 / 4);
  cast_bf16_kernel<<<1048576 / 1024, 256, 0, stream>>>(wk, wqkv + 4194304, 1048576 / 4);
  cast_bf16_kernel<<<1048576 / 1024, 256, 0, stream>>>(wv, wqkv + 5242880, 1048576 / 4);
  cast_bf16_kernel<<<4194304 / 1024, 256, 0, stream>>>(wo, wob, 4194304 / 4);

  // fused QKV projection: qkv = xb @ wqkv^T   (M=4096, N=3072, K=2048)
  gemm_bt_128<<<dim3(3072 / 128, 4096 / 128), 256, 0, stream>>>(xb, wqkv, qkv, 4096, 3072, 2048);

  // RoPE + bf16 materialization
  rope_kernel<<<(4096 * 1536) / 256, 256, 0, stream>>>(qkv, fc, fs, qbuf, kbuf, vbuf);

  // flash attention
  attn_kernel<<<dim3(32, 16, 2), 256, 0, stream>>>(qbuf, kbuf, vbuf, ybuf);

  // output projection: out = y @ wo^T   (M=4096, N=2048, K=2048)
  gemm_bt_128<<<dim3(2048 / 128, 4096 / 128), 256, 0, stream>>>(ybuf, wob, out, 4096, 2048, 2048);
}

// Round 2
// 380.727 us; speedup vs baseline: 1.5928x; 1.5928x over previous
//
#include <hip/hip_runtime.h>

typedef __attribute__((ext_vector_type(8))) __bf16 bf16x8;
typedef __attribute__((ext_vector_type(4))) __bf16 bf16x4;
typedef __attribute__((ext_vector_type(4))) float floatx4;

#define MFMA16x16x32 __builtin_amdgcn_mfma_f32_16x16x32_bf16

// async 16B/lane global->LDS. LDS dest must be wave-uniform; lane i lands at l + i*16.
__device__ __forceinline__ void async_load16(const void* g, void* l) {
  __builtin_amdgcn_global_load_lds((const __attribute__((address_space(1))) void*)g,
                                   (__attribute__((address_space(3))) void*)l, 16, 0, 0);
}

// ---------------- cast fp32 -> bf16 (vectorized x4) ----------------
__global__ void cast_bf16_kernel(const float* __restrict__ src, __bf16* __restrict__ dst, int n4) {
  int i = blockIdx.x * blockDim.x + threadIdx.x;
  if (i < n4) {
    const float4* s4 = (const float4*)src;
    float4 v = s4[i];
    bf16x4 o;
    o[0] = (__bf16)v.x; o[1] = (__bf16)v.y; o[2] = (__bf16)v.z; o[3] = (__bf16)v.w;
    *(bf16x4*)(dst + (size_t)i * 4) = o;
  }
}

// ---------------- GEMM: C(M,N) fp32 = A(M,K) @ B(N,K)^T, bf16, m97-style ----------------
// 128x128 tile, BK=64, global_load_lds staging, XOR-swizzled LDS (seg ^= row&7).
__global__ __launch_bounds__(256) void gemm_bt(const __bf16* __restrict__ A,
                                               const __bf16* __restrict__ Bw,
                                               float* __restrict__ C,
                                               int M, int N, int K) {
  __shared__ __bf16 As[128][64];
  __shared__ __bf16 Bs[128][64];
  const int tid = threadIdx.x;
  const int wave = tid >> 6, lane = tid & 63;
  const int quad = lane >> 4, l16 = lane & 15;
  const int wm = (wave >> 1) * 64, wn = (wave & 1) * 64;
  const int row0 = blockIdx.y * 128, col0 = blockIdx.x * 128;
  const int lr = lane >> 3, ls = lane & 7;
  const int segg = ls ^ lr;  // swizzled source segment for this lane
  floatx4 acc[4][4] = {};
  const __bf16* Ab = A + (size_t)row0 * K + segg * 8;
  const __bf16* Bb = Bw + (size_t)col0 * K + segg * 8;
  for (int k0 = 0; k0 < K; k0 += 64) {
    __syncthreads();
#pragma unroll
    for (int i = 0; i < 4; i++) {
      int c = wave * 4 + i;  // chunk = 8 rows x 64 els = 1 KB
      int r = c * 8 + lr;
      async_load16(Ab + (size_t)r * K + k0, &As[c * 8][0]);
      async_load16(Bb + (size_t)r * K + k0, &Bs[c * 8][0]);
    }
    __syncthreads();
#pragma unroll
    for (int kk = 0; kk < 64; kk += 32) {
      bf16x8 af[4], bfr[4];
#pragma unroll
      for (int mt = 0; mt < 4; mt++) {
        int row = wm + mt * 16 + l16;
        int seg = ((kk >> 3) + quad) ^ (row & 7);
        af[mt] = *(const bf16x8*)&As[row][seg * 8];
      }
#pragma unroll
      for (int nt = 0; nt < 4; nt++) {
        int row = wn + nt * 16 + l16;
        int seg = ((kk >> 3) + quad) ^ (row & 7);
        bfr[nt] = *(const bf16x8*)&Bs[row][seg * 8];
      }
#pragma unroll
      for (int mt = 0; mt < 4; mt++)
#pragma unroll
        for (int nt = 0; nt < 4; nt++)
          acc[mt][nt] = MFMA16x16x32(af[mt], bfr[nt], acc[mt][nt], 0, 0, 0);
    }
  }
#pragma unroll
  for (int mt = 0; mt < 4; mt++)
#pragma unroll
    for (int nt = 0; nt < 4; nt++)
#pragma unroll
      for (int r = 0; r < 4; r++) {
        int row = row0 + wm + mt * 16 + quad * 4 + r;
        int col = col0 + wn + nt * 16 + l16;
        C[(size_t)row * N + col] = acc[mt][nt][r];
      }
}

// ---------------- RoPE: qkv fp32 -> q,k bf16 (interleaved pairs) ----------------
__global__ void rope_kernel(const float* __restrict__ qkv, const float* __restrict__ cs,
                            const float* __restrict__ sn, __bf16* __restrict__ qb,
                            __bf16* __restrict__ kb) {
  int idx = blockIdx.x * blockDim.x + threadIdx.x;  // 4096*1280
  int row = idx / 1280, slot = idx - row * 1280;
  int t = row & 2047;
  const float* base = qkv + (size_t)row * 3072;
  if (slot < 1024) {  // q pairs
    int i = slot & 63;
    float x0 = base[2 * slot], x1 = base[2 * slot + 1];
    float c = cs[t * 64 + i], s = sn[t * 64 + i];
    qb[(size_t)row * 2048 + 2 * slot]     = (__bf16)(x0 * c - x1 * s);
    qb[(size_t)row * 2048 + 2 * slot + 1] = (__bf16)(x0 * s + x1 * c);
  } else {            // k pairs
    int ks = slot - 1024;
    int i = ks & 63;
    float x0 = base[2048 + 2 * ks], x1 = base[2048 + 2 * ks + 1];
    float c = cs[t * 64 + i], s = sn[t * 64 + i];
    kb[(size_t)row * 512 + 2 * ks]     = (__bf16)(x0 * c - x1 * s);
    kb[(size_t)row * 512 + 2 * ks + 1] = (__bf16)(x0 * s + x1 * c);
  }
}

// ---------------- V transpose: qkv[:,2560+c] fp32 -> Vt_g[(b*512+c)][t] bf16 ----------------
__global__ __launch_bounds__(256) void vtrans_kernel(const float* __restrict__ qkv,
                                                     __bf16* __restrict__ vtg) {
  __shared__ float Ts[32][33];
  const int t0 = blockIdx.x * 32, c0 = blockIdx.y * 32, b = blockIdx.z;
  const int tx = threadIdx.x & 31, ty = threadIdx.x >> 5;  // ty 0..7
#pragma unroll
  for (int j = 0; j < 4; j++) {
    int tr = ty * 4 + j;
    Ts[tr][tx] = qkv[(size_t)(b * 2048 + t0 + tr) * 3072 + 2560 + c0 + tx];
  }
  __syncthreads();
#pragma unroll
  for (int j = 0; j < 4; j++) {
    int tc = ty * 4 + j;
    vtg[(size_t)(b * 512 + c0 + tc) * 2048 + t0 + tx] = (__bf16)Ts[tx][tc];
  }
}

// ---------------- Flash attention, causal, GQA; 1 wave per WG ----------------
// grid (pair=32, h=16, b=2), 64 threads. WG handles q-tiles `pair` and `63-pair`
// (32 rows each) => uniform 33 iterations of 64 keys. K and Vt staged via
// global_load_lds with XOR swizzle; V pre-transposed in global.
__global__ __launch_bounds__(64) void attn_kernel(const __bf16* __restrict__ qb,
                                                  const __bf16* __restrict__ kb,
                                                  const __bf16* __restrict__ vtg,
                                                  __bf16* __restrict__ yb) {
  const int pair = blockIdx.x, h = blockIdx.y, b = blockIdx.z;
  const int kvh = h >> 2;
  const int lane = threadIdx.x;
  const int quad = lane >> 4, l16 = lane & 15;
  __shared__ __bf16 Ks[64][128];  // [key][dim], swizzled segs
  __shared__ __bf16 Vt[128][64];  // [dim][key], swizzled segs
  __shared__ __bf16 Ps[32][72];   // P tile [qrow][key], padded
  const __bf16* kbase = kb + (size_t)b * 2048 * 512 + kvh * 128;
  const __bf16* vbase = vtg + ((size_t)b * 512 + kvh * 128) * 2048;
  const float scale = 0.08838834764831845f;  // 1/sqrt(128)
  const int klr4 = lane >> 4, kls = lane & 15;           // K staging: 4 rows/chunk
  const int vlr8 = lane >> 3, vls = lane & 7;            // V staging: 8 rows/chunk
  for (int ph = 0; ph < 2; ph++) {
    const int tile = ph ? (63 - pair) : pair;
    const int q0 = tile * 32;
    bf16x8 qf[2][4];
#pragma unroll
    for (int mt = 0; mt < 2; mt++)
#pragma unroll
      for (int kc = 0; kc < 4; kc++)
        qf[mt][kc] = *(const bf16x8*)(qb + (size_t)(b * 2048 + q0 + mt * 16 + l16) * 2048 +
                                      h * 128 + kc * 32 + quad * 8);
    floatx4 o[2][8] = {};
    float m_r[2][4], l_r[2][4];
#pragma unroll
    for (int mt = 0; mt < 2; mt++)
#pragma unroll
      for (int r = 0; r < 4; r++) { m_r[mt][r] = -1e30f; l_r[mt][r] = 0.f; }
    const int nblocks = (q0 + 95) >> 6;  // ceil((q0+32)/64)
    for (int it = 0; it < nblocks; it++) {
      const int s0 = it * 64;
      __syncthreads();  // drain prev iter's LDS reads before DMA overwrite
      // stage K: 64 keys x 128 dims, 16 chunks of (4 rows x 128B)
#pragma unroll
      for (int c = 0; c < 16; c++) {
        int row = c * 4 + klr4;
        int sg = kls ^ (row & 7);
        async_load16(kbase + (size_t)(s0 + row) * 512 + sg * 8, &Ks[c * 4][0]);
      }
      // stage Vt: 128 dims x 64 keys, 16 chunks of (8 rows x 128B)
#pragma unroll
      for (int c = 0; c < 16; c++) {
        int d = c * 8 + vlr8;
        int sg = vls ^ (d & 7);
        async_load16(vbase + (size_t)d * 2048 + s0 + sg * 8, &Vt[c * 8][0]);
      }
      __syncthreads();  // staging complete
      // QK^T
      floatx4 sacc[2][4] = {};
#pragma unroll
      for (int kc = 0; kc < 4; kc++) {
        bf16x8 bfr[4];
#pragma unroll
        for (int nt = 0; nt < 4; nt++) {
          int key = nt * 16 + l16;
          int seg = (kc * 4 + quad) ^ (key & 7);
          bfr[nt] = *(const bf16x8*)&Ks[key][seg * 8];
        }
#pragma unroll
        for (int mt = 0; mt < 2; mt++)
#pragma unroll
          for (int nt = 0; nt < 4; nt++)
            sacc[mt][nt] = MFMA16x16x32(qf[mt][kc], bfr[nt], sacc[mt][nt], 0, 0, 0);
      }
      // online softmax (rows spread over quad*4+r; keys over nt*16+l16)
      float alpha[2][4];
#pragma unroll
      for (int mt = 0; mt < 2; mt++)
#pragma unroll
        for (int r = 0; r < 4; r++) {
          int qg = q0 + mt * 16 + quad * 4 + r;
          float sv[4], mb = -1e30f;
#pragma unroll
          for (int nt = 0; nt < 4; nt++) {
            int keyg = s0 + nt * 16 + l16;
            sv[nt] = (keyg <= qg) ? sacc[mt][nt][r] * scale : -1e30f;
            mb = fmaxf(mb, sv[nt]);
          }
#pragma unroll
          for (int off = 8; off >= 1; off >>= 1) mb = fmaxf(mb, __shfl_xor(mb, off));
          float mn = fmaxf(m_r[mt][r], mb);
          float a = __expf(m_r[mt][r] - mn);
          float ls = 0.f;
#pragma unroll
          for (int nt = 0; nt < 4; nt++) {
            float p = __expf(sv[nt] - mn);
            Ps[mt * 16 + quad * 4 + r][nt * 16 + l16] = (__bf16)p;
            ls += p;
          }
#pragma unroll
          for (int off = 8; off >= 1; off >>= 1) ls += __shfl_xor(ls, off);
          l_r[mt][r] = l_r[mt][r] * a + ls;
          m_r[mt][r] = mn;
          alpha[mt][r] = a;
        }
      __syncthreads();  // Ps visible (cross-lane via LDS)
#pragma unroll
      for (int mt = 0; mt < 2; mt++)
#pragma unroll
        for (int dt = 0; dt < 8; dt++)
#pragma unroll
          for (int r = 0; r < 4; r++) o[mt][dt][r] *= alpha[mt][r];
      // P @ V
#pragma unroll
      for (int c2 = 0; c2 < 2; c2++) {
        bf16x8 pa[2];
#pragma unroll
        for (int mt = 0; mt < 2; mt++)
          pa[mt] = *(const bf16x8*)&Ps[mt * 16 + l16][c2 * 32 + quad * 8];
#pragma unroll
        for (int dt = 0; dt < 8; dt++) {
          int row = dt * 16 + l16;
          int seg = (c2 * 4 + quad) ^ (row & 7);
          bf16x8 vf = *(const bf16x8*)&Vt[row][seg * 8];
#pragma unroll
          for (int mt = 0; mt < 2; mt++)
            o[mt][dt] = MFMA16x16x32(pa[mt], vf, o[mt][dt], 0, 0, 0);
        }
      }
    }
    // epilogue for this q-tile
#pragma unroll
    for (int mt = 0; mt < 2; mt++) {
      float inv[4];
#pragma unroll
      for (int r = 0; r < 4; r++) inv[r] = 1.f / l_r[mt][r];
#pragma unroll
      for (int dt = 0; dt < 8; dt++)
#pragma unroll
        for (int r = 0; r < 4; r++) {
          int qg = q0 + mt * 16 + quad * 4 + r;
          yb[(size_t)(b * 2048 + qg) * 2048 + h * 128 + dt * 16 + l16] =
              (__bf16)(o[mt][dt][r] * inv[r]);
        }
    }
  }
}

// ---------------- host ----------------
extern "C" void kernel_launch(void* const* d_in, const int* in_sizes, int n_in,
                              void* d_out, int out_size, void* d_ws, size_t ws_size,
                              hipStream_t stream) {
  const float* x  = (const float*)d_in[0];
  const float* fc = (const float*)d_in[1];
  const float* fs = (const float*)d_in[2];
  const float* wq = (const float*)d_in[3];
  const float* wk = (const float*)d_in[4];
  const float* wv = (const float*)d_in[5];
  const float* wo = (const float*)d_in[6];
  float* out = (float*)d_out;
  char* ws = (char*)d_ws;

  __bf16* xb   = (__bf16*)(ws);              // 4096x2048 bf16
  __bf16* wqkv = (__bf16*)(ws + 16777216);   // 3072x2048 bf16
  __bf16* wob  = (__bf16*)(ws + 29360128);   // 2048x2048 bf16
  float*  qkv  = (float*) (ws + 37748736);   // 4096x3072 fp32
  __bf16* kbuf = (__bf16*)(ws + 88080384);   // 4096x512 bf16
  __bf16* vtg  = (__bf16*)(ws + 92274688);   // 1024x2048 bf16 (V^T per b,kvh)
  __bf16* qbuf = xb;                          // alias: xb dead after GEMM1
  __bf16* ybuf = (__bf16*)(ws + 37748736);    // alias: qkv dead after rope+vtrans

  cast_bf16_kernel<<<8388608 / 1024, 256, 0, stream>>>(x, xb, 8388608 / 4);
  cast_bf16_kernel<<<4194304 / 1024, 256, 0, stream>>>(wq, wqkv, 4194304 / 4);
  cast_bf16_kernel<<<1048576 / 1024, 256, 0, stream>>>(wk, wqkv + 4194304, 1048576 / 4);
  cast_bf16_kernel<<<1048576 / 1024, 256, 0, stream>>>(wv, wqkv + 5242880, 1048576 / 4);
  cast_bf16_kernel<<<4194304 / 1024, 256, 0, stream>>>(wo, wob, 4194304 / 4);

  // QKV projection: qkv = xb @ wqkv^T (M=4096, N=3072, K=2048)
  gemm_bt<<<dim3(24, 32), 256, 0, stream>>>(xb, wqkv, qkv, 4096, 3072, 2048);

  // RoPE q,k -> bf16; V transpose -> bf16 [d][t]
  rope_kernel<<<(4096 * 1280) / 256, 256, 0, stream>>>(qkv, fc, fs, qbuf, kbuf);
  vtrans_kernel<<<dim3(64, 16, 2), 256, 0, stream>>>(qkv, vtg);

  // flash attention (1024 one-wave WGs, uniform work via tile pairing)
  attn_kernel<<<dim3(32, 16, 2), 64, 0, stream>>>(qbuf, kbuf, vtg, ybuf);

  // output projection: out = y @ wo^T (M=4096, N=2048, K=2048)
  gemm_bt<<<dim3(16, 32), 256, 0, stream>>>(ybuf, wob, out, 4096, 2048, 2048);
}